// Round 1
// 873.427 us; speedup vs baseline: 1.0463x; 1.0463x over previous
//
#include <hip/hip_runtime.h>

// B=16,S=1024,E=1024,F=4096,H=16,D=64. N = B*S = 16384 tokens.
// Pipeline: LN1 -> QKV gemm(bf16 MFMA)+bias -> MFMA flash attn (S^T softmax) ->
//           proj gemm+bias+resid -> d_out -> LN2 -> lin1 gemm+bias+GELU ->
//           lin2 gemm+bias+resid(in-place d_out). FFN single-pass if ws allows, else 2-chunk.
//
// GEMM engine: 256x256 tile, BK=64, 512 thr (8 waves 2Mx4N), double-buffered 128 KB LDS,
// 8-phase counted-vmcnt schedule (T3+T4+T5 per cdna_hip_programming.md §5/§5.5) +
// bijective XCD-chunked block swizzle (T1). Staging keeps the proven global-side XOR
// chunk swizzle (0 bank conflicts measured on the 128^2 predecessor).
//
// Workspace plan:
//   0          wqkv_b  bf16 3072x1024   (6 MB)
//   6291456    wo_b    bf16 1024x1024   (2 MB)
//   8388608    w1_b    bf16 4096x1024   (8 MB)
//   16777216   w2_b    bf16 1024x4096   (8 MB)
//   25165824   region1 (32 MB): xn_b -> ctx_b -> xn2_b
//   58720256   region2: qkv_b (96 MB) -> h (128 MB single-pass if ws_size>=184MiB,
//                                            else 64 MB chunks, 2-pass)
// x1 (fp32) lives in d_out; lin2 updates d_out in place (same-thread R->W).

typedef __attribute__((ext_vector_type(8))) short bf16x8;
typedef __attribute__((ext_vector_type(4))) float f32x4;
typedef __attribute__((ext_vector_type(8))) unsigned short u16x8;
typedef __attribute__((ext_vector_type(4))) unsigned short u16x4;

__device__ __forceinline__ float bf2f(unsigned short u) {
    return __uint_as_float(((unsigned int)u) << 16);
}
__device__ __forceinline__ unsigned short f2bf(float f) {
    unsigned int u = __float_as_uint(f);
    u += 0x7fffu + ((u >> 16) & 1u);   // RNE
    return (unsigned short)(u >> 16);
}
// pack two positive f32 into bf16x2 dword by truncation (P in [0,1])
__device__ __forceinline__ unsigned int pkbf_trunc(float a, float b) {
    return (__float_as_uint(a) >> 16) | (__float_as_uint(b) & 0xffff0000u);
}

// async global->LDS, 16 B per lane; LDS dest is wave-uniform base + lane*16
__device__ __forceinline__ void gload_lds16(const unsigned short* g, unsigned short* l) {
    __builtin_amdgcn_global_load_lds(
        (const __attribute__((address_space(1))) unsigned int*)g,
        (__attribute__((address_space(3))) unsigned int*)l, 16, 0, 0);
}

// compiler memory fence (free) + raw barrier: does NOT drain vmcnt (unlike __syncthreads)
#define FENCE() asm volatile("" ::: "memory")
#define BAR()                         \
    do {                              \
        FENCE();                      \
        __builtin_amdgcn_s_barrier(); \
        FENCE();                      \
    } while (0)
#define VMCNT(n)                                               \
    do {                                                       \
        asm volatile("s_waitcnt vmcnt(" #n ")" ::: "memory");  \
        __builtin_amdgcn_sched_barrier(0);                     \
    } while (0)

// ---------------- fp32 -> bf16 weight conversion ----------------
__global__ __launch_bounds__(256) void cvt_kernel(const float* __restrict__ in,
                                                  unsigned short* __restrict__ out, int n4) {
    int i = blockIdx.x * 256 + threadIdx.x;
    if (i >= n4) return;
    float4 v = ((const float4*)in)[i];
    u16x4 o;
    o[0] = f2bf(v.x); o[1] = f2bf(v.y); o[2] = f2bf(v.z); o[3] = f2bf(v.w);
    ((u16x4*)out)[i] = o;
}

// ---------------- LayerNorm (E=1024), fp32 in -> bf16 out ----------------
__global__ __launch_bounds__(256) void ln_kernel(const float* __restrict__ x,
                                                 const float* __restrict__ w,
                                                 const float* __restrict__ b,
                                                 unsigned short* __restrict__ out) {
    const int row = blockIdx.x;
    const int t = threadIdx.x;
    const float* xr = x + (size_t)row * 1024;
    float4 v = *(const float4*)(xr + t * 4);
    float s = v.x + v.y + v.z + v.w;
    float sq = v.x * v.x + v.y * v.y + v.z * v.z + v.w * v.w;
#pragma unroll
    for (int off = 32; off > 0; off >>= 1) {
        s += __shfl_xor(s, off);
        sq += __shfl_xor(sq, off);
    }
    __shared__ float rs_[4], rq_[4];
    if ((t & 63) == 0) { rs_[t >> 6] = s; rq_[t >> 6] = sq; }
    __syncthreads();
    s = rs_[0] + rs_[1] + rs_[2] + rs_[3];
    sq = rq_[0] + rq_[1] + rq_[2] + rq_[3];
    const float mu = s * (1.0f / 1024.0f);
    const float var = sq * (1.0f / 1024.0f) - mu * mu;
    const float rstd = rsqrtf(var + 1e-5f);
    const int c = t * 4;
    float4 wv = *(const float4*)(w + c);
    float4 bv = *(const float4*)(b + c);
    u16x4 o;
    o[0] = f2bf((v.x - mu) * rstd * wv.x + bv.x);
    o[1] = f2bf((v.y - mu) * rstd * wv.y + bv.y);
    o[2] = f2bf((v.z - mu) * rstd * wv.z + bv.z);
    o[3] = f2bf((v.w - mu) * rstd * wv.w + bv.w);
    *(u16x4*)(out + (size_t)row * 1024 + c) = o;
}

// ---------------- bf16 MFMA GEMM: C[M,N] = A[M,K] @ Bt[N,K]^T + epilogue ----------------
// 256x256 tile, BK=64, 512 threads (8 waves as 2x4 of 128x64), double-buffered LDS
// (buf = K-tile parity). 8 phases per 2 K-tiles; per phase:
//   {ds_read 4-12 x b128 || issue one half-tile (2x global_load_lds) -> s_barrier ->
//    setprio(1) 16x mfma_16x16x32_bf16 setprio(0) -> s_barrier}
// vmcnt(4) only at phases 4 and 8 (2 half-tiles stay in flight across barriers).
// Stage order: p1/p2 = A of tile T+1 (buf1); p3/p4 = B of T+2 (buf0); p5/p6 = A of T+2;
// p7/p8 = B of T+3 (buf1). WAR safe: every phase's ds_reads are consumed by that phase's
// MFMA (lgkm drained before the phase's closing barrier), and each buffer region's
// overwrite is issued >=1 barrier after its last read phase.
// Staging swizzle: LDS slot s of row r holds global chunk s^(r&7) (pre-swizzled global
// source, linear LDS dest as global_load_lds requires).
// EPI: 0 bias->bf16 ; 1 bias+resid->f32 ; 2 bias+GELU->bf16
// Requires M%256==0, N%256==0, K%128==0, K>=256.
template <int EPI>
__global__ __launch_bounds__(512, 2) void gemm_bt(const unsigned short* __restrict__ A,
                                                  const unsigned short* __restrict__ Bt,
                                                  const float* __restrict__ bias,
                                                  const float* __restrict__ resid,
                                                  void* __restrict__ outp,
                                                  int M, int N, int K) {
    __shared__ __align__(16) unsigned short sA[2][256 * 64];
    __shared__ __align__(16) unsigned short sB[2][256 * 64];
    const int t = threadIdx.x;
    const int lane = t & 63;
    const int w = t >> 6;            // 0..7
    const int wm = w >> 2;           // 0..1  (wave M index)
    const int wn = w & 3;            // 0..3  (wave N index)
    const int quad = lane >> 4;
    const int cl = lane & 15;

    // XCD-chunked bijective swizzle (all launches here have nwg % 8 == 0):
    // XCD k gets a contiguous run of logical tiles -> A-panel sharers on one L2.
    const int nwg = gridDim.x * gridDim.y;
    int wg = blockIdx.y * gridDim.x + blockIdx.x;
    wg = (wg & 7) * (nwg >> 3) + (wg >> 3);
    const int mBase = (wg / gridDim.x) * 256;
    const int nBase = (wg % gridDim.x) * 256;

    // staging lane geometry: wave w, instr u covers rows (w*2+u)*8 .. +7 of a 128-row half
    const int rl = lane >> 3;                  // row within 8-row group
    const int ch = ((lane & 7) ^ rl) * 8;      // swizzled global chunk (element offset)
    const unsigned short* gA = A + (size_t)mBase * K;
    const unsigned short* gB = Bt + (size_t)nBase * K;

#define STAGE_A(buf, hf, k0)                                                          \
    do {                                                                              \
        _Pragma("unroll") for (int u_ = 0; u_ < 2; ++u_) {                            \
            const int r_ = (hf) * 128 + (w * 2 + u_) * 8;                             \
            gload_lds16(gA + (size_t)(r_ + rl) * K + (k0) + ch, &sA[buf][r_ * 64]);   \
        }                                                                             \
    } while (0)
#define STAGE_B(buf, hf, k0)                                                          \
    do {                                                                              \
        _Pragma("unroll") for (int u_ = 0; u_ < 2; ++u_) {                            \
            const int r_ = (hf) * 128 + (w * 2 + u_) * 8;                             \
            gload_lds16(gB + (size_t)(r_ + rl) * K + (k0) + ch, &sB[buf][r_ * 64]);   \
        }                                                                             \
    } while (0)
#define READ_B8(buf)                                                                  \
    do {                                                                              \
        _Pragma("unroll") for (int nf_ = 0; nf_ < 4; ++nf_) {                         \
            const int rb_ = wn * 64 + nf_ * 16 + cl;                                  \
            _Pragma("unroll") for (int ks_ = 0; ks_ < 2; ++ks_)                       \
                bf[nf_][ks_] = *(const bf16x8*)(&sB[buf][rb_ * 64 +                   \
                                     (((quad + 4 * ks_) ^ (rb_ & 7)) * 8)]);          \
        }                                                                             \
    } while (0)
#define READ_A2(buf, mfb)                                                             \
    do {                                                                              \
        _Pragma("unroll") for (int m_ = 0; m_ < 2; ++m_) {                            \
            const int ra_ = wm * 128 + ((mfb) + m_) * 16 + cl;                        \
            _Pragma("unroll") for (int ks_ = 0; ks_ < 2; ++ks_)                       \
                af[m_][ks_] = *(const bf16x8*)(&sA[buf][ra_ * 64 +                    \
                                     (((quad + 4 * ks_) ^ (ra_ & 7)) * 8)]);          \
        }                                                                             \
    } while (0)
#define MFMA_Q(q)                                                                     \
    do {                                                                              \
        __builtin_amdgcn_s_setprio(1);                                                \
        _Pragma("unroll") for (int m_ = 0; m_ < 2; ++m_)                              \
            _Pragma("unroll") for (int nf_ = 0; nf_ < 4; ++nf_)                       \
                _Pragma("unroll") for (int ks_ = 0; ks_ < 2; ++ks_)                   \
                    acc[2 * (q) + m_][nf_] = __builtin_amdgcn_mfma_f32_16x16x32_bf16( \
                        af[m_][ks_], bf[nf_][ks_], acc[2 * (q) + m_][nf_], 0, 0, 0);  \
        __builtin_amdgcn_s_setprio(0);                                                \
    } while (0)

    f32x4 acc[8][4] = {};
    bf16x8 bf[4][2];   // B frags of current K-tile (live 4 phases)
    bf16x8 af[2][2];   // A frags of current phase (transient)

    // ---- prologue: T0 {A,B} -> buf0, T1 {B} -> buf1; leave T1-B (4 loads) in flight
    STAGE_A(0, 0, 0); STAGE_A(0, 1, 0);
    STAGE_B(0, 0, 0); STAGE_B(0, 1, 0);
    STAGE_B(1, 0, 64); STAGE_B(1, 1, 64);
    VMCNT(4);
    BAR();

    const int NI = K >> 7;                     // iterations of 2 K-tiles
    for (int i = 0; i < NI; ++i) {
        const bool more = (i + 1 < NI);
        const int kT1 = (i << 7) + 64;         // k of tile T+1
        const int kN = (i + 1) << 7;           // k of tile T+2 (T+3 at kN+64)
        // ---- p1: tile T (buf0), quadrant 0 ----
        READ_B8(0); READ_A2(0, 0);
        STAGE_A(1, 0, kT1);
        BAR(); MFMA_Q(0); BAR();
        // ---- p2 ----
        READ_A2(0, 2);
        STAGE_A(1, 1, kT1);
        BAR(); MFMA_Q(1); BAR();
        // ---- p3 ----
        READ_A2(0, 4);
        if (more) STAGE_B(0, 0, kN);
        BAR(); MFMA_Q(2); BAR();
        // ---- p4: gate for tile T+1 (T+2-B stays in flight) ----
        READ_A2(0, 6);
        if (more) STAGE_B(0, 1, kN);
        BAR(); MFMA_Q(3);
        if (more) { VMCNT(4); } else { VMCNT(0); }
        BAR();
        // ---- p5: tile T+1 (buf1) ----
        READ_B8(1); READ_A2(1, 0);
        if (more) STAGE_A(0, 0, kN);
        BAR(); MFMA_Q(0); BAR();
        // ---- p6 ----
        READ_A2(1, 2);
        if (more) STAGE_A(0, 1, kN);
        BAR(); MFMA_Q(1); BAR();
        // ---- p7 ----
        READ_A2(1, 4);
        if (more) STAGE_B(1, 0, kN + 64);
        BAR(); MFMA_Q(2); BAR();
        // ---- p8: gate for tile T+2 (T+3-B stays in flight) ----
        READ_A2(1, 6);
        if (more) STAGE_B(1, 1, kN + 64);
        BAR(); MFMA_Q(3);
        if (more) VMCNT(4);
        BAR();
    }

    // C/D layout: col = lane&15, row = quad*4 + reg
#pragma unroll
    for (int mf = 0; mf < 8; ++mf) {
        const int rowg = mBase + wm * 128 + mf * 16 + quad * 4;
#pragma unroll
        for (int nf = 0; nf < 4; ++nf) {
            const int colg = nBase + wn * 64 + nf * 16 + cl;
            const float bv = bias[colg];
#pragma unroll
            for (int rr = 0; rr < 4; ++rr) {
                const float v = acc[mf][nf][rr] + bv;
                const size_t idx = (size_t)(rowg + rr) * N + colg;
                if constexpr (EPI == 0) {
                    ((unsigned short*)outp)[idx] = f2bf(v);
                } else if constexpr (EPI == 1) {
                    ((float*)outp)[idx] = v + resid[idx];
                } else {
                    const float g = 0.5f * v * (1.0f + erff(v * 0.70710678118654752f));
                    ((unsigned short*)outp)[idx] = f2bf(g);
                }
            }
        }
    }
#undef STAGE_A
#undef STAGE_B
#undef READ_B8
#undef READ_A2
#undef MFMA_Q
}

// ---------------- MFMA flash attention, 128 q-rows/block, S^T softmax ----------------
// Block = 256 threads (4 waves). blockIdx.x = b*16+h, blockIdx.y = 128-row q-tile.
// Wave w owns q-rows qt*128 + w*32 .. +31 (two 16-row subs). Per 64-key tile:
//   S^T = mfma(K_frag, Q_frag): D[key=quad*4+rr (+i*16)][q=cl] — A/B frag layouts are
//   identical for 16x16x32, so operand swap is free. Each lane owns all 64 key-scores
//   of q=cl: max = 15 fmax + 2 shfl_xor(16,32); P packed to uint2 (trunc bf16, keys
//   consecutive) -> 4 ds_write_b64/sub; l rides a 5th PV accumulator vs ones B-frag
//   (same trunc P -> normalization-consistent); alpha rebroadcast to O rows via 4 shfl.
// LDS: Ks 9216 + Vt 9216 + Ps 18432 = 36.9 KB. 2 barriers/tile.
__global__ __launch_bounds__(256) void attn_mfma(const unsigned short* __restrict__ qkv,
                                                 unsigned short* __restrict__ ctx) {
    __shared__ __align__(16) unsigned short Ks[64 * 72];
    __shared__ __align__(16) unsigned int Vt[64 * 36];
    __shared__ __align__(16) unsigned short Ps[128 * 72];

    const int bh = blockIdx.x;
    const int qt = blockIdx.y;
    const int b = bh >> 4;
    const int h = bh & 15;
    const int t = threadIdx.x;
    const int w = t >> 6;
    const int lane = t & 63;
    const int quad = lane >> 4;
    const int cl = lane & 15;
    const size_t tok0 = (size_t)b * 1024;
    const int qrow0 = qt * 128 + w * 32;

    // Q fragments: operand [idx=cl][k=quad*8 + ks*32] (A/B identical layout)
    bf16x8 aq[2][2];
#pragma unroll
    for (int sub = 0; sub < 2; ++sub) {
        const unsigned short* qp =
            qkv + (tok0 + qrow0 + sub * 16 + cl) * 3072 + h * 64 + quad * 8;
        aq[sub][0] = *(const bf16x8*)(qp);
        aq[sub][1] = *(const bf16x8*)(qp + 32);
    }

    const bf16x8 vones = {0x3F80, 0x3F80, 0x3F80, 0x3F80, 0x3F80, 0x3F80, 0x3F80, 0x3F80};

    // staging indices
    const int r0 = t >> 2;         // K row 0..63
    const int c16 = (t & 3) * 16;  // K col chunk
    const int kp = t >> 3;         // V key-pair 0..31
    const int dc = t & 7;          // V d-chunk (8 d's)

    f32x4 acc[2][5] = {};          // [sub][j]; j=4 is the l-column (ones B-frag)
    float m_r[2] = {-3.0e38f, -3.0e38f};   // running max for q=cl, per sub

    for (int kt = 0; kt < 16; ++kt) {
        // ---- stage K [key][d] and V^T [d][key-pair dword] ----
        {
            const unsigned short* kg =
                qkv + (tok0 + kt * 64 + r0) * 3072 + 1024 + h * 64 + c16;
            *(int4*)(Ks + r0 * 72 + c16) = *(const int4*)(kg);
            *(int4*)(Ks + r0 * 72 + c16 + 8) = *(const int4*)(kg + 8);

            const unsigned short* vg =
                qkv + (tok0 + kt * 64 + 2 * kp) * 3072 + 2048 + h * 64 + dc * 8;
            u16x8 v0 = *(const u16x8*)(vg);
            u16x8 v1 = *(const u16x8*)(vg + 3072);
            const int g = kp >> 2, wd = kp & 3;
#pragma unroll
            for (int j = 0; j < 8; ++j) {
                const int d = dc * 8 + j;
                Vt[d * 36 + (((g ^ (d >> 3)) << 2) | wd)] =
                    ((unsigned int)v1[j] << 16) | (unsigned int)v0[j];
            }
        }
        __syncthreads();

#pragma unroll
        for (int sub = 0; sub < 2; ++sub) {
            // ---- S^T = K·Q^T (operand-swapped MFMA) ----
            f32x4 sc[4] = {};
#pragma unroll
            for (int i = 0; i < 4; ++i) {
                const int rb = i * 16 + cl;
#pragma unroll
                for (int ks = 0; ks < 2; ++ks) {
                    bf16x8 bk = *(const bf16x8*)(Ks + rb * 72 + quad * 8 + ks * 32);
                    sc[i] = __builtin_amdgcn_mfma_f32_16x16x32_bf16(bk, aq[sub][ks], sc[i],
                                                                    0, 0, 0);
                }
            }
            // ---- softmax for q = cl: all 64 key-scores live in this lane + 3 quad-mates
            float mx0 = fmaxf(fmaxf(sc[0][0], sc[0][1]), fmaxf(sc[0][2], sc[0][3]));
            float mx1 = fmaxf(fmaxf(sc[1][0], sc[1][1]), fmaxf(sc[1][2], sc[1][3]));
            float mx2 = fmaxf(fmaxf(sc[2][0], sc[2][1]), fmaxf(sc[2][2], sc[2][3]));
            float mx3 = fmaxf(fmaxf(sc[3][0], sc[3][1]), fmaxf(sc[3][2], sc[3][3]));
            float rmax = fmaxf(fmaxf(mx0, mx1), fmaxf(mx2, mx3));
            rmax = fmaxf(rmax, __shfl_xor(rmax, 16));
            rmax = fmaxf(rmax, __shfl_xor(rmax, 32));
            const float mnew = fmaxf(m_r[sub], rmax * 0.125f);
            const float alpha = __expf(m_r[sub] - mnew);
            m_r[sub] = mnew;
            // alpha for this lane's O rows (q = quad*4+rr) from lane cl'=quad*4+rr
            float al[4];
#pragma unroll
            for (int rr = 0; rr < 4; ++rr) al[rr] = __shfl(alpha, quad * 4 + rr, 16);
#pragma unroll
            for (int j = 0; j < 5; ++j)
#pragma unroll
                for (int rr = 0; rr < 4; ++rr) acc[sub][j][rr] *= al[rr];
            // P = exp(S - m) for 16 consecutive-key values; pack & store as 2 dwords/i
            const unsigned short* pr = Ps + (w * 32 + sub * 16 + cl) * 72;
#pragma unroll
            for (int i = 0; i < 4; ++i) {
                const float p0 = __expf(fmaf(sc[i][0], 0.125f, -mnew));
                const float p1 = __expf(fmaf(sc[i][1], 0.125f, -mnew));
                const float p2 = __expf(fmaf(sc[i][2], 0.125f, -mnew));
                const float p3 = __expf(fmaf(sc[i][3], 0.125f, -mnew));
                uint2 pk;
                pk.x = pkbf_trunc(p0, p1);
                pk.y = pkbf_trunc(p2, p3);
                *(uint2*)(pr + i * 16 + quad * 4) = pk;
            }
        }

        // ---- PV (+ l via ones-column) ----
#pragma unroll
        for (int ks = 0; ks < 2; ++ks) {
            bf16x8 bv[4];
#pragma unroll
            for (int j = 0; j < 4; ++j) {
                const int d = j * 16 + cl;
                bv[j] = *(const bf16x8*)(Vt + d * 36 + (((quad + 4 * ks) ^ (d >> 3)) << 2));
            }
#pragma unroll
            for (int sub = 0; sub < 2; ++sub) {
                bf16x8 ap =
                    *(const bf16x8*)(Ps + (w * 32 + sub * 16 + cl) * 72 + quad * 8 + ks * 32);
#pragma unroll
                for (int j = 0; j < 4; ++j)
                    acc[sub][j] =
                        __builtin_amdgcn_mfma_f32_16x16x32_bf16(ap, bv[j], acc[sub][j], 0, 0, 0);
                acc[sub][4] =
                    __builtin_amdgcn_mfma_f32_16x16x32_bf16(ap, vones, acc[sub][4], 0, 0, 0);
            }
        }
        __syncthreads();  // Ks/Vt reads done before next staging
    }

    // ---- epilogue: O = acc / l (l = ones-column), bf16 store ----
#pragma unroll
    for (int sub = 0; sub < 2; ++sub)
#pragma unroll
        for (int rr = 0; rr < 4; ++rr) {
            const float inv = 1.0f / acc[sub][4][rr];
            const size_t tok = tok0 + qt * 128 + w * 32 + sub * 16 + quad * 4 + rr;
#pragma unroll
            for (int j = 0; j < 4; ++j)
                ctx[tok * 1024 + h * 64 + j * 16 + cl] = f2bf(acc[sub][j][rr] * inv);
        }
}

extern "C" void kernel_launch(void* const* d_in, const int* in_sizes, int n_in,
                              void* d_out, int out_size, void* d_ws, size_t ws_size,
                              hipStream_t stream) {
    const float* x    = (const float*)d_in[0];
    const float* wqkv = (const float*)d_in[1];
    const float* bqkv = (const float*)d_in[2];
    const float* wo   = (const float*)d_in[3];
    const float* bo   = (const float*)d_in[4];
    const float* w1   = (const float*)d_in[5];
    const float* b1   = (const float*)d_in[6];
    const float* w2   = (const float*)d_in[7];
    const float* b2   = (const float*)d_in[8];
    const float* n1w  = (const float*)d_in[9];
    const float* n1b  = (const float*)d_in[10];
    const float* n2w  = (const float*)d_in[11];
    const float* n2b  = (const float*)d_in[12];
    float* out = (float*)d_out;   // also serves as x1 (residual stream after attention)

    char* ws = (char*)d_ws;
    unsigned short* wqkv_b = (unsigned short*)(ws);
    unsigned short* wo_b   = (unsigned short*)(ws + 6291456);
    unsigned short* w1_b   = (unsigned short*)(ws + 8388608);
    unsigned short* w2_b   = (unsigned short*)(ws + 16777216);
    unsigned short* r1     = (unsigned short*)(ws + 25165824);  // xn -> ctx -> xn2
    unsigned short* r2     = (unsigned short*)(ws + 58720256);  // qkv -> h

    unsigned short* xn_b  = r1;
    unsigned short* ctx_b = r1;
    unsigned short* xn2_b = r1;
    unsigned short* qkv_b = r2;
    unsigned short* h_b   = r2;

    cvt_kernel<<<3072, 256, 0, stream>>>(wqkv, wqkv_b, 786432);
    cvt_kernel<<<1024, 256, 0, stream>>>(wo, wo_b, 262144);
    cvt_kernel<<<4096, 256, 0, stream>>>(w1, w1_b, 1048576);
    cvt_kernel<<<4096, 256, 0, stream>>>(w2, w2_b, 1048576);

    ln_kernel<<<16384, 256, 0, stream>>>(x, n1w, n1b, xn_b);
    gemm_bt<0><<<dim3(12, 64), 512, 0, stream>>>(xn_b, wqkv_b, bqkv, nullptr, qkv_b,
                                                 16384, 3072, 1024);
    attn_mfma<<<dim3(256, 8), 256, 0, stream>>>(qkv_b, ctx_b);
    gemm_bt<1><<<dim3(4, 64), 512, 0, stream>>>(ctx_b, wo_b, bo, x, out, 16384, 1024, 1024);
    ln_kernel<<<16384, 256, 0, stream>>>(out, n2w, n2b, xn2_b);

    // FFN: single pass if h (128 MB @ region2) fits, else 2 row-chunks of 8192 tokens.
    // ws_size is constant across calls -> branch is graph-capture safe.
    if (ws_size >= 192937984ULL) {
        gemm_bt<2><<<dim3(16, 64), 512, 0, stream>>>(xn2_b, w1_b, b1, nullptr, h_b,
                                                     16384, 4096, 1024);
        gemm_bt<1><<<dim3(4, 64), 512, 0, stream>>>(h_b, w2_b, b2, out, out,
                                                    16384, 1024, 4096);
    } else {
        for (int c = 0; c < 2; ++c) {
            const size_t row0 = (size_t)c * 8192;
            gemm_bt<2><<<dim3(16, 32), 512, 0, stream>>>(xn2_b + row0 * 1024, w1_b, b1,
                                                         nullptr, h_b, 8192, 4096, 1024);
            gemm_bt<1><<<dim3(4, 32), 512, 0, stream>>>(h_b, w2_b, b2, out + row0 * 1024,
                                                        out + row0 * 1024, 8192, 1024, 4096);
        }
    }
}